// Round 2
// baseline (4329.497 us; speedup 1.0000x reference)
//
#include <hip/hip_runtime.h>
#include <hip/hip_bf16.h>

#define N_NODES 50000
#define N_EDGES 800000
#define N_GRAPHS 64
#define DIM 64
#define N_GIN 4
#define N_PRED 5
#define BN_EPS 1e-5f

__device__ __forceinline__ float b2f(__hip_bfloat16 v) { return __bfloat162float(v); }

// dtype-adaptive load: isb=1 -> bf16, isb=0 -> fp32 (index in ELEMENTS)
__device__ __forceinline__ float loadv(const void* p, size_t i, int isb) {
    return isb ? b2f(((const __hip_bfloat16*)p)[i]) : ((const float*)p)[i];
}

// order-preserving float -> uint encoding for atomicMax-based segment_max
__device__ __forceinline__ unsigned int enc_f(float f) {
    unsigned int b = __float_as_uint(f);
    return (b & 0x80000000u) ? ~b : (b | 0x80000000u);
}
__device__ __forceinline__ float dec_f(unsigned int u) {
    unsigned int b = (u & 0x80000000u) ? (u ^ 0x80000000u) : ~u;
    return __uint_as_float(b);
}

// Detect bf16 vs fp32 layout of x. For bf16 pairs, word bits[14:7] are the
// low element's exponent field, clustered in [0x70,0x85] for N(0,1) data;
// for fp32 those bits are uniform random mantissa (~9% in range).
__global__ void detect_dtype(const unsigned int* __restrict__ xw, int* __restrict__ flag) {
    __shared__ int cnt[256];
    int t = threadIdx.x;
    int c = 0;
    for (int i = t; i < 1024; i += 256) {
        unsigned int e = (xw[i] >> 7) & 0xFFu;
        if (e >= 0x70u && e <= 0x85u) c++;
    }
    cnt[t] = c;
    __syncthreads();
    for (int s = 128; s > 0; s >>= 1) {
        if (t < s) cnt[t] += cnt[t + s];
        __syncthreads();
    }
    if (t == 0) *flag = (cnt[0] >= 512) ? 1 : 0;
}

__global__ void zero_u32(unsigned int* __restrict__ p, int n) {
    int i = blockIdx.x * blockDim.x + threadIdx.x;
    if (i < n) p[i] = 0u;
}

__global__ void convert_pool(const void* __restrict__ x, float* __restrict__ A,
                             const int* __restrict__ batch, unsigned int* __restrict__ poolEnc,
                             const int* __restrict__ dflag) {
    int isb = *dflag;
    int idx = blockIdx.x * blockDim.x + threadIdx.x;
    if (idx >= N_NODES * DIM) return;
    int i = idx >> 6, c = idx & 63;
    float v = loadv(x, idx, isb);
    A[idx] = v;
    atomicMax(&poolEnc[batch[i] * DIM + c], enc_f(v));
}

__global__ void copy_f4(const float4* __restrict__ A, float4* __restrict__ B, int n4) {
    int i = blockIdx.x * blockDim.x + threadIdx.x;
    if (i < n4) B[i] = A[i];
}

// B[dst] += A[src] over edges; 1 thread per (edge, 4-channel chunk)
__global__ void edge_scatter(const int* __restrict__ src, const int* __restrict__ dst,
                             const float* __restrict__ A, float* __restrict__ B) {
    int idx = blockIdx.x * blockDim.x + threadIdx.x;
    if (idx >= N_EDGES * 16) return;
    int e = idx >> 4, q = idx & 15;
    int s = src[e], d = dst[e];
    float4 v = ((const float4*)(A + (size_t)s * DIM))[q];
    float* bp = B + (size_t)d * DIM + (q << 2);
    atomicAdd(bp + 0, v.x);
    atomicAdd(bp + 1, v.y);
    atomicAdd(bp + 2, v.z);
    atomicAdd(bp + 3, v.w);
}

// Y = [relu](X @ W + b) for one layer; weight/bias element offsets passed in.
// Optionally accumulate per-feature sum/sumsq into double stats.
template <bool RELU, bool STATS>
__global__ void mm64(const float* __restrict__ X, const void* __restrict__ W, size_t wOff,
                     const void* __restrict__ bias, size_t bOff, float* __restrict__ Y,
                     double* __restrict__ stats, const int* __restrict__ dflag) {
    int isb = *dflag;
    __shared__ float Ws[64][64];
    __shared__ float Xs[4][64];
    __shared__ float Sv[4][64];
    __shared__ float bsh[64];
    int tid = threadIdx.x;
    for (int i = tid; i < 4096; i += 256) Ws[i >> 6][i & 63] = loadv(W, wOff + i, isb);
    if (tid < 64) bsh[tid] = loadv(bias, bOff + tid, isb);
    int r = tid >> 6, d = tid & 63;
    int row = blockIdx.x * 4 + r;
    Xs[r][d] = X[(size_t)row * DIM + d];
    __syncthreads();
    float acc = bsh[d];
#pragma unroll
    for (int k = 0; k < 64; k++) acc += Xs[r][k] * Ws[k][d];
    if (RELU) acc = acc > 0.0f ? acc : 0.0f;
    Y[(size_t)row * DIM + d] = acc;
    if (STATS) {
        Sv[r][d] = acc;
        __syncthreads();
        if (tid < 64) {
            float s = 0.0f, s2 = 0.0f;
#pragma unroll
            for (int rr = 0; rr < 4; rr++) {
                float v = Sv[rr][tid];
                s += v;
                s2 += v * v;
            }
            atomicAdd(&stats[tid], (double)s);
            atomicAdd(&stats[64 + tid], (double)s2);
        }
    }
}

__global__ void bn_prelu_pool(const float* __restrict__ Z, float* __restrict__ H,
                              const double* __restrict__ stats,
                              const void* __restrict__ gamma, const void* __restrict__ beta,
                              size_t gOff, const void* __restrict__ alpha_p,
                              const int* __restrict__ batch,
                              unsigned int* __restrict__ poolEnc,
                              const int* __restrict__ dflag) {
    int isb = *dflag;
    int idx = blockIdx.x * blockDim.x + threadIdx.x;
    if (idx >= N_NODES * DIM) return;
    int i = idx >> 6, c = idx & 63;
    double m = stats[c] * (1.0 / N_NODES);
    double var = stats[64 + c] * (1.0 / N_NODES) - m * m;
    float inv = rsqrtf(fmaxf((float)var, 0.0f) + BN_EPS);
    float z = Z[idx];
    float v = (z - (float)m) * inv * loadv(gamma, gOff + c, isb) + loadv(beta, gOff + c, isb);
    float alpha = loadv(alpha_p, 0, isb);
    v = v > 0.0f ? v : alpha * v;
    H[idx] = v;
    atomicMax(&poolEnc[batch[i] * DIM + c], enc_f(v));
}

// out[g*320 + d*5 + l] = sum_k pooled[l][g][k] * predW[l][k][d] + predB[l][d]
__global__ void pred_head(const unsigned int* __restrict__ poolEnc,
                          const void* __restrict__ predW, const void* __restrict__ predB,
                          void* __restrict__ out, const int* __restrict__ dflag) {
    int isb = *dflag;
    int l = blockIdx.x / N_GRAPHS;
    int g = blockIdx.x % N_GRAPHS;
    int d = threadIdx.x;
    __shared__ float ps[64];
    ps[d] = dec_f(poolEnc[(size_t)l * N_GRAPHS * DIM + g * DIM + d]);
    __syncthreads();
    float acc = loadv(predB, (size_t)l * DIM + d, isb);
    size_t wbase = (size_t)l * DIM * DIM;
#pragma unroll
    for (int k = 0; k < 64; k++) acc += ps[k] * loadv(predW, wbase + k * DIM + d, isb);
    int o = g * (DIM * N_PRED) + d * N_PRED + l;
    if (isb) ((__hip_bfloat16*)out)[o] = __float2bfloat16(acc);
    else ((float*)out)[o] = acc;
}

extern "C" void kernel_launch(void* const* d_in, const int* in_sizes, int n_in,
                              void* d_out, int out_size, void* d_ws, size_t ws_size,
                              hipStream_t stream) {
    const void* x     = d_in[0];
    const int*  edge  = (const int*)d_in[1];
    const int*  batch = (const int*)d_in[2];
    const void* W1    = d_in[3];
    const void* b1    = d_in[4];
    const void* W2    = d_in[5];
    const void* b2    = d_in[6];
    const void* gamma = d_in[7];
    const void* beta  = d_in[8];
    const void* alpha = d_in[9];
    const void* pW    = d_in[10];
    const void* pB    = d_in[11];

    float* A = (float*)d_ws;                               // 12.8 MB
    float* B = A + (size_t)N_NODES * DIM;                  // 12.8 MB
    double* stats = (double*)(B + (size_t)N_NODES * DIM);  // 128 doubles
    unsigned int* poolEnc = (unsigned int*)(stats + 128);  // 20480 u32
    int* dflag = (int*)(poolEnc + N_PRED * N_GRAPHS * DIM);

    const int* esrc = edge;
    const int* edst = edge + N_EDGES;
    const int ND = N_NODES * DIM;  // 3,200,000 = 12500*256

    detect_dtype<<<1, 256, 0, stream>>>((const unsigned int*)x, dflag);
    zero_u32<<<(N_PRED * N_GRAPHS * DIM + 255) / 256, 256, 0, stream>>>(poolEnc,
                                                                        N_PRED * N_GRAPHS * DIM);
    convert_pool<<<ND / 256, 256, 0, stream>>>(x, A, batch, poolEnc, dflag);

    for (int l = 0; l < N_GIN; l++) {
        size_t wOff = (size_t)l * DIM * DIM;
        size_t bOff = (size_t)l * DIM;
        copy_f4<<<(ND / 4 + 255) / 256, 256, 0, stream>>>((const float4*)A, (float4*)B, ND / 4);
        edge_scatter<<<(N_EDGES * 16) / 256, 256, 0, stream>>>(esrc, edst, A, B);
        mm64<true, false><<<N_NODES / 4, 256, 0, stream>>>(B, W1, wOff, b1, bOff, A, nullptr,
                                                           dflag);
        zero_u32<<<1, 256, 0, stream>>>((unsigned int*)stats, 256);
        mm64<false, true><<<N_NODES / 4, 256, 0, stream>>>(A, W2, wOff, b2, bOff, B, stats,
                                                           dflag);
        bn_prelu_pool<<<ND / 256, 256, 0, stream>>>(
            B, A, stats, gamma, beta, bOff, alpha, batch,
            poolEnc + (size_t)(l + 1) * N_GRAPHS * DIM, dflag);
    }
    pred_head<<<N_PRED * N_GRAPHS, DIM, 0, stream>>>(poolEnc, pW, pB, d_out, dflag);
}

// Round 3
// 1886.267 us; speedup vs baseline: 2.2953x; 2.2953x over previous
//
#include <hip/hip_runtime.h>
#include <hip/hip_bf16.h>

#define N_NODES 50000
#define N_EDGES 800000
#define N_GRAPHS 64
#define DIM 64
#define N_GIN 4
#define N_PRED 5
#define BN_EPS 1e-5f
#define SCAN_BLOCKS 196  // ceil(50000/256)

__device__ __forceinline__ float b2f(__hip_bfloat16 v) { return __bfloat162float(v); }

// dtype-adaptive load: isb=1 -> bf16, isb=0 -> fp32 (index in ELEMENTS)
__device__ __forceinline__ float loadv(const void* p, size_t i, int isb) {
    return isb ? b2f(((const __hip_bfloat16*)p)[i]) : ((const float*)p)[i];
}

// order-preserving float -> uint encoding for atomicMax-based segment_max
__device__ __forceinline__ unsigned int enc_f(float f) {
    unsigned int b = __float_as_uint(f);
    return (b & 0x80000000u) ? ~b : (b | 0x80000000u);
}
__device__ __forceinline__ float dec_f(unsigned int u) {
    unsigned int b = (u & 0x80000000u) ? (u ^ 0x80000000u) : ~u;
    return __uint_as_float(b);
}

// Detect bf16 vs fp32 layout of x (see round-1 notes). bf16 data: word bits
// [14:7] = low element's exponent, clustered [0x70,0x85] for N(0,1).
__global__ void detect_dtype(const unsigned int* __restrict__ xw, int* __restrict__ flag) {
    __shared__ int cnt[256];
    int t = threadIdx.x;
    int c = 0;
    for (int i = t; i < 1024; i += 256) {
        unsigned int e = (xw[i] >> 7) & 0xFFu;
        if (e >= 0x70u && e <= 0x85u) c++;
    }
    cnt[t] = c;
    __syncthreads();
    for (int s = 128; s > 0; s >>= 1) {
        if (t < s) cnt[t] += cnt[t + s];
        __syncthreads();
    }
    if (t == 0) *flag = (cnt[0] >= 512) ? 1 : 0;
}

__global__ void zero_u32(unsigned int* __restrict__ p, int n) {
    int i = blockIdx.x * blockDim.x + threadIdx.x;
    if (i < n) p[i] = 0u;
}

__global__ void convert_pool(const void* __restrict__ x, float* __restrict__ A,
                             const int* __restrict__ batch, unsigned int* __restrict__ poolEnc,
                             const int* __restrict__ dflag) {
    int isb = *dflag;
    int idx = blockIdx.x * blockDim.x + threadIdx.x;
    if (idx >= N_NODES * DIM) return;
    int i = idx >> 6, c = idx & 63;
    float v = loadv(x, idx, isb);
    A[idx] = v;
    atomicMax(&poolEnc[batch[i] * DIM + c], enc_f(v));
}

// ---------------- CSR build (once per call) ----------------

__global__ void hist_deg(const int* __restrict__ dst, unsigned int* __restrict__ deg) {
    int e = blockIdx.x * blockDim.x + threadIdx.x;
    if (e < N_EDGES) atomicAdd(&deg[dst[e]], 1u);
}

__global__ void deg_block_sums(const unsigned int* __restrict__ deg,
                               unsigned int* __restrict__ bsum) {
    __shared__ unsigned int sh[256];
    int t = threadIdx.x;
    int i = blockIdx.x * 256 + t;
    sh[t] = (i < N_NODES) ? deg[i] : 0u;
    __syncthreads();
    for (int s = 128; s > 0; s >>= 1) {
        if (t < s) sh[t] += sh[t + s];
        __syncthreads();
    }
    if (t == 0) bsum[blockIdx.x] = sh[0];
}

// exclusive scan of SCAN_BLOCKS block sums, in place (single block)
__global__ void scan_bsums(unsigned int* __restrict__ bsum) {
    __shared__ unsigned int sh[256];
    int t = threadIdx.x;
    unsigned int orig = (t < SCAN_BLOCKS) ? bsum[t] : 0u;
    sh[t] = orig;
    __syncthreads();
    for (int off = 1; off < 256; off <<= 1) {
        unsigned int v = (t >= off) ? sh[t - off] : 0u;
        __syncthreads();
        sh[t] += v;
        __syncthreads();
    }
    if (t < SCAN_BLOCKS) bsum[t] = sh[t] - orig;  // exclusive
}

// rowptr[i] = bsum_excl[blk] + in-block exclusive scan; cursor[i] = rowptr[i]
__global__ void scan_write(const unsigned int* __restrict__ deg,
                           const unsigned int* __restrict__ bsum,
                           unsigned int* __restrict__ rowptr,
                           unsigned int* __restrict__ cursor) {
    __shared__ unsigned int sh[256];
    int t = threadIdx.x;
    int i = blockIdx.x * 256 + t;
    unsigned int orig = (i < N_NODES) ? deg[i] : 0u;
    sh[t] = orig;
    __syncthreads();
    for (int off = 1; off < 256; off <<= 1) {
        unsigned int v = (t >= off) ? sh[t - off] : 0u;
        __syncthreads();
        sh[t] += v;
        __syncthreads();
    }
    if (i < N_NODES) {
        unsigned int r = bsum[blockIdx.x] + sh[t] - orig;
        rowptr[i] = r;
        cursor[i] = r;
    }
}

__global__ void fill_csr(const int* __restrict__ src, const int* __restrict__ dst,
                         unsigned int* __restrict__ cursor, unsigned int* __restrict__ srclist) {
    int e = blockIdx.x * blockDim.x + threadIdx.x;
    if (e < N_EDGES) {
        unsigned int p = atomicAdd(&cursor[dst[e]], 1u);
        srclist[p] = (unsigned int)src[e];
    }
}

// B[i] = A[i] + sum_{j in CSR[i]} A[srclist[j]]   (GIN aggregation, no atomics)
__global__ void gather_agg(const float* __restrict__ A, float* __restrict__ B,
                           const unsigned int* __restrict__ rowptr,
                           const unsigned int* __restrict__ deg,
                           const unsigned int* __restrict__ srclist) {
    int tid = threadIdx.x;
    int node = blockIdx.x * 4 + (tid >> 6);
    int c = tid & 63;
    unsigned int start = rowptr[node];
    unsigned int cnt = deg[node];
    float s = A[(size_t)node * DIM + c];
    const unsigned int* sl = srclist + start;
    unsigned int j = 0;
    for (; j + 1 < cnt; j += 2) {
        unsigned int s0 = sl[j], s1 = sl[j + 1];
        s += A[(size_t)s0 * DIM + c] + A[(size_t)s1 * DIM + c];
    }
    if (j < cnt) s += A[(size_t)sl[j] * DIM + c];
    B[(size_t)node * DIM + c] = s;
}

// ---------------- fallback (atomic) aggregation ----------------

__global__ void copy_f4(const float4* __restrict__ A, float4* __restrict__ B, int n4) {
    int i = blockIdx.x * blockDim.x + threadIdx.x;
    if (i < n4) B[i] = A[i];
}

__global__ void edge_scatter(const int* __restrict__ src, const int* __restrict__ dst,
                             const float* __restrict__ A, float* __restrict__ B) {
    int idx = blockIdx.x * blockDim.x + threadIdx.x;
    if (idx >= N_EDGES * 16) return;
    int e = idx >> 4, q = idx & 15;
    int s = src[e], d = dst[e];
    float4 v = ((const float4*)(A + (size_t)s * DIM))[q];
    float* bp = B + (size_t)d * DIM + (q << 2);
    atomicAdd(bp + 0, v.x);
    atomicAdd(bp + 1, v.y);
    atomicAdd(bp + 2, v.z);
    atomicAdd(bp + 3, v.w);
}

// ---------------- dense layers ----------------

// Y = [relu](X @ W + b); optional per-feature sum/sumsq into double stats
template <bool RELU, bool STATS>
__global__ void mm64(const float* __restrict__ X, const void* __restrict__ W, size_t wOff,
                     const void* __restrict__ bias, size_t bOff, float* __restrict__ Y,
                     double* __restrict__ stats, const int* __restrict__ dflag) {
    int isb = *dflag;
    __shared__ float Ws[64][64];
    __shared__ float Xs[4][64];
    __shared__ float Sv[4][64];
    __shared__ float bsh[64];
    int tid = threadIdx.x;
    for (int i = tid; i < 4096; i += 256) Ws[i >> 6][i & 63] = loadv(W, wOff + i, isb);
    if (tid < 64) bsh[tid] = loadv(bias, bOff + tid, isb);
    int r = tid >> 6, d = tid & 63;
    int row = blockIdx.x * 4 + r;
    Xs[r][d] = X[(size_t)row * DIM + d];
    __syncthreads();
    float acc = bsh[d];
#pragma unroll
    for (int k = 0; k < 64; k++) acc += Xs[r][k] * Ws[k][d];
    if (RELU) acc = acc > 0.0f ? acc : 0.0f;
    Y[(size_t)row * DIM + d] = acc;
    if (STATS) {
        Sv[r][d] = acc;
        __syncthreads();
        if (tid < 64) {
            float s = 0.0f, s2 = 0.0f;
#pragma unroll
            for (int rr = 0; rr < 4; rr++) {
                float v = Sv[rr][tid];
                s += v;
                s2 += v * v;
            }
            atomicAdd(&stats[tid], (double)s);
            atomicAdd(&stats[64 + tid], (double)s2);
        }
    }
}

__global__ void bn_prelu_pool(const float* __restrict__ Z, float* __restrict__ H,
                              const double* __restrict__ stats,
                              const void* __restrict__ gamma, const void* __restrict__ beta,
                              size_t gOff, const void* __restrict__ alpha_p,
                              const int* __restrict__ batch,
                              unsigned int* __restrict__ poolEnc,
                              const int* __restrict__ dflag) {
    int isb = *dflag;
    int idx = blockIdx.x * blockDim.x + threadIdx.x;
    if (idx >= N_NODES * DIM) return;
    int i = idx >> 6, c = idx & 63;
    double m = stats[c] * (1.0 / N_NODES);
    double var = stats[64 + c] * (1.0 / N_NODES) - m * m;
    float inv = rsqrtf(fmaxf((float)var, 0.0f) + BN_EPS);
    float z = Z[idx];
    float v = (z - (float)m) * inv * loadv(gamma, gOff + c, isb) + loadv(beta, gOff + c, isb);
    float alpha = loadv(alpha_p, 0, isb);
    v = v > 0.0f ? v : alpha * v;
    H[idx] = v;
    atomicMax(&poolEnc[batch[i] * DIM + c], enc_f(v));
}

// out[g*320 + d*5 + l] = sum_k pooled[l][g][k] * predW[l][k][d] + predB[l][d]
__global__ void pred_head(const unsigned int* __restrict__ poolEnc,
                          const void* __restrict__ predW, const void* __restrict__ predB,
                          void* __restrict__ out, const int* __restrict__ dflag) {
    int isb = *dflag;
    int l = blockIdx.x / N_GRAPHS;
    int g = blockIdx.x % N_GRAPHS;
    int d = threadIdx.x;
    __shared__ float ps[64];
    ps[d] = dec_f(poolEnc[(size_t)l * N_GRAPHS * DIM + g * DIM + d]);
    __syncthreads();
    float acc = loadv(predB, (size_t)l * DIM + d, isb);
    size_t wbase = (size_t)l * DIM * DIM;
#pragma unroll
    for (int k = 0; k < 64; k++) acc += ps[k] * loadv(predW, wbase + k * DIM + d, isb);
    int o = g * (DIM * N_PRED) + d * N_PRED + l;
    if (isb) ((__hip_bfloat16*)out)[o] = __float2bfloat16(acc);
    else ((float*)out)[o] = acc;
}

extern "C" void kernel_launch(void* const* d_in, const int* in_sizes, int n_in,
                              void* d_out, int out_size, void* d_ws, size_t ws_size,
                              hipStream_t stream) {
    const void* x     = d_in[0];
    const int*  edge  = (const int*)d_in[1];
    const int*  batch = (const int*)d_in[2];
    const void* W1    = d_in[3];
    const void* b1    = d_in[4];
    const void* W2    = d_in[5];
    const void* b2    = d_in[6];
    const void* gamma = d_in[7];
    const void* beta  = d_in[8];
    const void* alpha = d_in[9];
    const void* pW    = d_in[10];
    const void* pB    = d_in[11];

    float* A = (float*)d_ws;                               // 12.8 MB
    float* B = A + (size_t)N_NODES * DIM;                  // 12.8 MB
    double* stats = (double*)(B + (size_t)N_NODES * DIM);  // 128 doubles
    unsigned int* poolEnc = (unsigned int*)(stats + 128);  // 20480 u32
    int* dflag = (int*)(poolEnc + N_PRED * N_GRAPHS * DIM);
    unsigned int* deg     = (unsigned int*)(dflag + 1);    // 50000
    unsigned int* rowptr  = deg + N_NODES;                 // 50000
    unsigned int* cursor  = rowptr + N_NODES;              // 50000
    unsigned int* bsum    = cursor + N_NODES;              // 256
    unsigned int* srclist = bsum + 256;                    // 800000

    size_t need = (size_t)((char*)(srclist + N_EDGES) - (char*)d_ws);
    bool useCSR = ws_size >= need;

    const int* esrc = edge;
    const int* edst = edge + N_EDGES;
    const int ND = N_NODES * DIM;  // 3,200,000 = 12500*256

    detect_dtype<<<1, 256, 0, stream>>>((const unsigned int*)x, dflag);
    zero_u32<<<(N_PRED * N_GRAPHS * DIM + 255) / 256, 256, 0, stream>>>(poolEnc,
                                                                        N_PRED * N_GRAPHS * DIM);
    convert_pool<<<ND / 256, 256, 0, stream>>>(x, A, batch, poolEnc, dflag);

    if (useCSR) {
        zero_u32<<<SCAN_BLOCKS, 256, 0, stream>>>(deg, N_NODES);
        hist_deg<<<(N_EDGES + 255) / 256, 256, 0, stream>>>(edst, deg);
        deg_block_sums<<<SCAN_BLOCKS, 256, 0, stream>>>(deg, bsum);
        scan_bsums<<<1, 256, 0, stream>>>(bsum);
        scan_write<<<SCAN_BLOCKS, 256, 0, stream>>>(deg, bsum, rowptr, cursor);
        fill_csr<<<(N_EDGES + 255) / 256, 256, 0, stream>>>(esrc, edst, cursor, srclist);
    }

    for (int l = 0; l < N_GIN; l++) {
        size_t wOff = (size_t)l * DIM * DIM;
        size_t bOff = (size_t)l * DIM;
        if (useCSR) {
            gather_agg<<<N_NODES / 4, 256, 0, stream>>>(A, B, rowptr, deg, srclist);
        } else {
            copy_f4<<<(ND / 4 + 255) / 256, 256, 0, stream>>>((const float4*)A, (float4*)B,
                                                              ND / 4);
            edge_scatter<<<(N_EDGES * 16) / 256, 256, 0, stream>>>(esrc, edst, A, B);
        }
        mm64<true, false><<<N_NODES / 4, 256, 0, stream>>>(B, W1, wOff, b1, bOff, A, nullptr,
                                                           dflag);
        zero_u32<<<1, 256, 0, stream>>>((unsigned int*)stats, 256);
        mm64<false, true><<<N_NODES / 4, 256, 0, stream>>>(A, W2, wOff, b2, bOff, B, stats,
                                                           dflag);
        bn_prelu_pool<<<ND / 256, 256, 0, stream>>>(
            B, A, stats, gamma, beta, bOff, alpha, batch,
            poolEnc + (size_t)(l + 1) * N_GRAPHS * DIM, dflag);
    }
    pred_head<<<N_PRED * N_GRAPHS, DIM, 0, stream>>>(poolEnc, pW, pB, d_out, dflag);
}

// Round 4
// 710.765 us; speedup vs baseline: 6.0913x; 2.6539x over previous
//
#include <hip/hip_runtime.h>
#include <hip/hip_bf16.h>

#define N_NODES 50000
#define N_EDGES 800000
#define N_GRAPHS 64
#define DIM 64
#define N_GIN 4
#define N_PRED 5
#define BN_EPS 1e-5f
#define SCAN_BLOCKS 196  // ceil(50000/256)

typedef short bf16x8 __attribute__((ext_vector_type(8)));
typedef float f32x4 __attribute__((ext_vector_type(4)));

__device__ __forceinline__ float b2f(__hip_bfloat16 v) { return __bfloat162float(v); }

// dtype-adaptive load: isb=1 -> bf16, isb=0 -> fp32 (index in ELEMENTS)
__device__ __forceinline__ float loadv(const void* p, size_t i, int isb) {
    return isb ? b2f(((const __hip_bfloat16*)p)[i]) : ((const float*)p)[i];
}

__device__ __forceinline__ unsigned short f2bu(float f) {
    __hip_bfloat16 h = __float2bfloat16(f);
    return *(unsigned short*)&h;
}
__device__ __forceinline__ float bu2f(unsigned short u) {
    __hip_bfloat16 h = *(__hip_bfloat16*)&u;
    return b2f(h);
}

// order-preserving float -> uint encoding for atomicMax-based segment_max
__device__ __forceinline__ unsigned int enc_f(float f) {
    unsigned int b = __float_as_uint(f);
    return (b & 0x80000000u) ? ~b : (b | 0x80000000u);
}
__device__ __forceinline__ float dec_f(unsigned int u) {
    unsigned int b = (u & 0x80000000u) ? (u ^ 0x80000000u) : ~u;
    return __uint_as_float(b);
}

// Detect bf16 vs fp32 layout of x (round-1 notes): bf16 words have bits[14:7]
// = low element's exponent, clustered [0x70,0x85] for N(0,1) data.
__global__ void detect_dtype(const unsigned int* __restrict__ xw, int* __restrict__ flag) {
    __shared__ int cnt[256];
    int t = threadIdx.x;
    int c = 0;
    for (int i = t; i < 1024; i += 256) {
        unsigned int e = (xw[i] >> 7) & 0xFFu;
        if (e >= 0x70u && e <= 0x85u) c++;
    }
    cnt[t] = c;
    __syncthreads();
    for (int s = 128; s > 0; s >>= 1) {
        if (t < s) cnt[t] += cnt[t + s];
        __syncthreads();
    }
    if (t == 0) *flag = (cnt[0] >= 512) ? 1 : 0;
}

__global__ void zero_u32(unsigned int* __restrict__ p, int n) {
    int i = blockIdx.x * blockDim.x + threadIdx.x;
    if (i < n) p[i] = 0u;
}

// x -> h (bf16), and pool x into poolEnc slot 0
__global__ void convert_pool_b(const void* __restrict__ x, unsigned short* __restrict__ H,
                               const int* __restrict__ batch,
                               unsigned int* __restrict__ poolEnc,
                               const int* __restrict__ dflag) {
    int isb = *dflag;
    int idx = blockIdx.x * blockDim.x + threadIdx.x;
    if (idx >= N_NODES * DIM) return;
    int i = idx >> 6, c = idx & 63;
    float v = loadv(x, idx, isb);
    H[idx] = f2bu(v);
    atomicMax(&poolEnc[batch[i] * DIM + c], enc_f(v));
}

// ---------------- CSR build (once per call) ----------------

__global__ void hist_deg(const int* __restrict__ dst, unsigned int* __restrict__ deg) {
    int e = blockIdx.x * blockDim.x + threadIdx.x;
    if (e < N_EDGES) atomicAdd(&deg[dst[e]], 1u);
}

__global__ void deg_block_sums(const unsigned int* __restrict__ deg,
                               unsigned int* __restrict__ bsum) {
    __shared__ unsigned int sh[256];
    int t = threadIdx.x;
    int i = blockIdx.x * 256 + t;
    sh[t] = (i < N_NODES) ? deg[i] : 0u;
    __syncthreads();
    for (int s = 128; s > 0; s >>= 1) {
        if (t < s) sh[t] += sh[t + s];
        __syncthreads();
    }
    if (t == 0) bsum[blockIdx.x] = sh[0];
}

__global__ void scan_bsums(unsigned int* __restrict__ bsum) {
    __shared__ unsigned int sh[256];
    int t = threadIdx.x;
    unsigned int orig = (t < SCAN_BLOCKS) ? bsum[t] : 0u;
    sh[t] = orig;
    __syncthreads();
    for (int off = 1; off < 256; off <<= 1) {
        unsigned int v = (t >= off) ? sh[t - off] : 0u;
        __syncthreads();
        sh[t] += v;
        __syncthreads();
    }
    if (t < SCAN_BLOCKS) bsum[t] = sh[t] - orig;  // exclusive
}

__global__ void scan_write(const unsigned int* __restrict__ deg,
                           const unsigned int* __restrict__ bsum,
                           unsigned int* __restrict__ rowptr,
                           unsigned int* __restrict__ cursor) {
    __shared__ unsigned int sh[256];
    int t = threadIdx.x;
    int i = blockIdx.x * 256 + t;
    unsigned int orig = (i < N_NODES) ? deg[i] : 0u;
    sh[t] = orig;
    __syncthreads();
    for (int off = 1; off < 256; off <<= 1) {
        unsigned int v = (t >= off) ? sh[t - off] : 0u;
        __syncthreads();
        sh[t] += v;
        __syncthreads();
    }
    if (i < N_NODES) {
        unsigned int r = bsum[blockIdx.x] + sh[t] - orig;
        rowptr[i] = r;
        cursor[i] = r;
    }
}

__global__ void fill_csr(const int* __restrict__ src, const int* __restrict__ dst,
                         unsigned int* __restrict__ cursor, unsigned int* __restrict__ srclist) {
    int e = blockIdx.x * blockDim.x + threadIdx.x;
    if (e < N_EDGES) {
        unsigned int p = atomicAdd(&cursor[dst[e]], 1u);
        srclist[p] = (unsigned int)src[e];
    }
}

// Xb[i] = H[i] + sum_{j in CSR[i]} H[srclist[j]]  (bf16 in, fp32 acc, bf16 out)
__global__ void gather_agg_b(const unsigned short* __restrict__ H,
                             unsigned short* __restrict__ Xb,
                             const unsigned int* __restrict__ rowptr,
                             const unsigned int* __restrict__ deg,
                             const unsigned int* __restrict__ srclist) {
    int tid = threadIdx.x;
    int node = blockIdx.x * 4 + (tid >> 6);
    int c = tid & 63;
    unsigned int start = rowptr[node];
    unsigned int cnt = deg[node];
    float s = bu2f(H[(size_t)node * DIM + c]);
    const unsigned int* sl = srclist + start;
    unsigned int j = 0;
    for (; j + 1 < cnt; j += 2) {
        unsigned int s0 = sl[j], s1 = sl[j + 1];
        s += bu2f(H[(size_t)s0 * DIM + c]) + bu2f(H[(size_t)s1 * DIM + c]);
    }
    if (j < cnt) s += bu2f(H[(size_t)sl[j] * DIM + c]);
    Xb[(size_t)node * DIM + c] = f2bu(s);
}

// ---------------- MFMA path ----------------

// Pack 8 weight matrices (W1 x4, W2 x4; each 64x64 row-major [k][n]) into
// 16x16x32_bf16 B-fragment order: P[mi][((t*2+s)*64 + lane)*8 + j] =
//   W[k = s*32 + (lane>>4)*8 + j][n = t*16 + (lane&15)]
__global__ void pack_w(const void* __restrict__ W1, const void* __restrict__ W2,
                       unsigned short* __restrict__ P, const int* __restrict__ dflag) {
    int isb = *dflag;
    int mi = blockIdx.x;  // 0..7
    const void* src = (mi < 4) ? W1 : W2;
    size_t off = (size_t)(mi & 3) * 4096;
    for (int it = 0; it < 16; it++) {
        int idx = it * 256 + threadIdx.x;
        int j = idx & 7, l = (idx >> 3) & 63, s = (idx >> 9) & 1, t = idx >> 10;
        int k = s * 32 + (l >> 4) * 8 + j;
        int n = t * 16 + (l & 15);
        P[(size_t)mi * 4096 + idx] = f2bu(loadv(src, off + (size_t)k * 64 + n, isb));
    }
}

// Y = [relu](X @ W + b). X: bf16 row-major [N][64]. P: packed frags.
// 4 waves/block, 16 rows/wave, 64 rows/block. N_NODES % 16 == 0 so a wave is
// fully valid iff r0 < N. No LDS, no barriers.
template <bool RELU>
__global__ void mm_mfma(const unsigned short* __restrict__ X,
                        const unsigned short* __restrict__ P,
                        const void* __restrict__ bias, size_t bOff,
                        void* __restrict__ Y, const int* __restrict__ dflag) {
    int isb = *dflag;
    int lane = threadIdx.x & 63;
    int w = threadIdx.x >> 6;
    int r0 = blockIdx.x * 64 + w * 16;
    if (r0 >= N_NODES) return;
    int m = lane & 15, q = lane >> 4;
    int row = r0 + m;

    const bf16x8* Xv = (const bf16x8*)X;
    const bf16x8* Pv = (const bf16x8*)P;
    bf16x8 a0 = Xv[(size_t)row * 8 + q];       // k = q*8 .. q*8+7
    bf16x8 a1 = Xv[(size_t)row * 8 + 4 + q];   // k = 32 + q*8 ..
    bf16x8 b[8];
#pragma unroll
    for (int i = 0; i < 8; i++) b[i] = Pv[(size_t)i * 64 + lane];

    f32x4 acc[4] = {{0.f, 0.f, 0.f, 0.f}, {0.f, 0.f, 0.f, 0.f},
                    {0.f, 0.f, 0.f, 0.f}, {0.f, 0.f, 0.f, 0.f}};
#pragma unroll
    for (int t = 0; t < 4; t++) {
        acc[t] = __builtin_amdgcn_mfma_f32_16x16x32_bf16(a0, b[t * 2 + 0], acc[t], 0, 0, 0);
        acc[t] = __builtin_amdgcn_mfma_f32_16x16x32_bf16(a1, b[t * 2 + 1], acc[t], 0, 0, 0);
    }
    // C/D: col = t*16 + (lane&15), row = r0 + (lane>>4)*4 + reg  [m89/m91]
#pragma unroll
    for (int t = 0; t < 4; t++) {
        int col = t * 16 + m;
        float bv = loadv(bias, bOff + col, isb);
        int rbase = r0 + q * 4;
#pragma unroll
        for (int reg = 0; reg < 4; reg++) {
            float v = acc[t][reg] + bv;
            size_t o = (size_t)(rbase + reg) * 64 + col;
            if (RELU) {
                v = v > 0.0f ? v : 0.0f;
                ((unsigned short*)Y)[o] = f2bu(v);
            } else {
                ((float*)Y)[o] = v;
            }
        }
    }
}

// per-column sum / sumsq of Z into double stats[128]
__global__ void col_stats(const float* __restrict__ Z, double* __restrict__ stats) {
    __shared__ float s1sh[256], s2sh[256];
    int tid = threadIdx.x;
    float s1 = 0.0f, s2 = 0.0f;
    for (int i = blockIdx.x * 256 + tid; i < N_NODES * DIM; i += 256 * 256) {
        float v = Z[i];
        s1 += v;
        s2 += v * v;
    }
    s1sh[tid] = s1;
    s2sh[tid] = s2;
    __syncthreads();
    if (tid < 64) {
        float a1 = 0.0f, a2 = 0.0f;
#pragma unroll
        for (int r = 0; r < 4; r++) {
            a1 += s1sh[tid + 64 * r];
            a2 += s2sh[tid + 64 * r];
        }
        atomicAdd(&stats[tid], (double)a1);
        atomicAdd(&stats[64 + tid], (double)a2);
    }
}

__global__ void bn_prelu_pool_b(const float* __restrict__ Z, unsigned short* __restrict__ H,
                                const double* __restrict__ stats,
                                const void* __restrict__ gamma, const void* __restrict__ beta,
                                size_t gOff, const void* __restrict__ alpha_p,
                                const int* __restrict__ batch,
                                unsigned int* __restrict__ poolEnc,
                                const int* __restrict__ dflag) {
    int isb = *dflag;
    int idx = blockIdx.x * blockDim.x + threadIdx.x;
    if (idx >= N_NODES * DIM) return;
    int i = idx >> 6, c = idx & 63;
    double mn = stats[c] * (1.0 / N_NODES);
    double var = stats[64 + c] * (1.0 / N_NODES) - mn * mn;
    float inv = rsqrtf(fmaxf((float)var, 0.0f) + BN_EPS);
    float z = Z[idx];
    float v = (z - (float)mn) * inv * loadv(gamma, gOff + c, isb) + loadv(beta, gOff + c, isb);
    float alpha = loadv(alpha_p, 0, isb);
    v = v > 0.0f ? v : alpha * v;
    H[idx] = f2bu(v);
    atomicMax(&poolEnc[batch[i] * DIM + c], enc_f(v));
}

// ---------------- fallback path (round-3 proven) ----------------

__global__ void convert_pool_f(const void* __restrict__ x, float* __restrict__ A,
                               const int* __restrict__ batch,
                               unsigned int* __restrict__ poolEnc,
                               const int* __restrict__ dflag) {
    int isb = *dflag;
    int idx = blockIdx.x * blockDim.x + threadIdx.x;
    if (idx >= N_NODES * DIM) return;
    int i = idx >> 6, c = idx & 63;
    float v = loadv(x, idx, isb);
    A[idx] = v;
    atomicMax(&poolEnc[batch[i] * DIM + c], enc_f(v));
}

__global__ void copy_f4(const float4* __restrict__ A, float4* __restrict__ B, int n4) {
    int i = blockIdx.x * blockDim.x + threadIdx.x;
    if (i < n4) B[i] = A[i];
}

__global__ void edge_scatter(const int* __restrict__ src, const int* __restrict__ dst,
                             const float* __restrict__ A, float* __restrict__ B) {
    int idx = blockIdx.x * blockDim.x + threadIdx.x;
    if (idx >= N_EDGES * 16) return;
    int e = idx >> 4, q = idx & 15;
    int s = src[e], d = dst[e];
    float4 v = ((const float4*)(A + (size_t)s * DIM))[q];
    float* bp = B + (size_t)d * DIM + (q << 2);
    atomicAdd(bp + 0, v.x);
    atomicAdd(bp + 1, v.y);
    atomicAdd(bp + 2, v.z);
    atomicAdd(bp + 3, v.w);
}

template <bool RELU, bool STATS>
__global__ void mm64(const float* __restrict__ X, const void* __restrict__ W, size_t wOff,
                     const void* __restrict__ bias, size_t bOff, float* __restrict__ Y,
                     double* __restrict__ stats, const int* __restrict__ dflag) {
    int isb = *dflag;
    __shared__ float Ws[64][64];
    __shared__ float Xs[4][64];
    __shared__ float Sv[4][64];
    __shared__ float bsh[64];
    int tid = threadIdx.x;
    for (int i = tid; i < 4096; i += 256) Ws[i >> 6][i & 63] = loadv(W, wOff + i, isb);
    if (tid < 64) bsh[tid] = loadv(bias, bOff + tid, isb);
    int r = tid >> 6, d = tid & 63;
    int row = blockIdx.x * 4 + r;
    Xs[r][d] = X[(size_t)row * DIM + d];
    __syncthreads();
    float acc = bsh[d];
#pragma unroll
    for (int k = 0; k < 64; k++) acc += Xs[r][k] * Ws[k][d];
    if (RELU) acc = acc > 0.0f ? acc : 0.0f;
    Y[(size_t)row * DIM + d] = acc;
    if (STATS) {
        Sv[r][d] = acc;
        __syncthreads();
        if (tid < 64) {
            float s = 0.0f, s2 = 0.0f;
#pragma unroll
            for (int rr = 0; rr < 4; rr++) {
                float v = Sv[rr][tid];
                s += v;
                s2 += v * v;
            }
            atomicAdd(&stats[tid], (double)s);
            atomicAdd(&stats[64 + tid], (double)s2);
        }
    }
}

__global__ void bn_prelu_pool_f(const float* __restrict__ Z, float* __restrict__ H,
                                const double* __restrict__ stats,
                                const void* __restrict__ gamma, const void* __restrict__ beta,
                                size_t gOff, const void* __restrict__ alpha_p,
                                const int* __restrict__ batch,
                                unsigned int* __restrict__ poolEnc,
                                const int* __restrict__ dflag) {
    int isb = *dflag;
    int idx = blockIdx.x * blockDim.x + threadIdx.x;
    if (idx >= N_NODES * DIM) return;
    int i = idx >> 6, c = idx & 63;
    double mn = stats[c] * (1.0 / N_NODES);
    double var = stats[64 + c] * (1.0 / N_NODES) - mn * mn;
    float inv = rsqrtf(fmaxf((float)var, 0.0f) + BN_EPS);
    float z = Z[idx];
    float v = (z - (float)mn) * inv * loadv(gamma, gOff + c, isb) + loadv(beta, gOff + c, isb);
    float alpha = loadv(alpha_p, 0, isb);
    v = v > 0.0f ? v : alpha * v;
    H[idx] = v;
    atomicMax(&poolEnc[batch[i] * DIM + c], enc_f(v));
}

// out[g*320 + d*5 + l] = sum_k pooled[l][g][k] * predW[l][k][d] + predB[l][d]
__global__ void pred_head(const unsigned int* __restrict__ poolEnc,
                          const void* __restrict__ predW, const void* __restrict__ predB,
                          void* __restrict__ out, const int* __restrict__ dflag) {
    int isb = *dflag;
    int l = blockIdx.x / N_GRAPHS;
    int g = blockIdx.x % N_GRAPHS;
    int d = threadIdx.x;
    __shared__ float ps[64];
    ps[d] = dec_f(poolEnc[(size_t)l * N_GRAPHS * DIM + g * DIM + d]);
    __syncthreads();
    float acc = loadv(predB, (size_t)l * DIM + d, isb);
    size_t wbase = (size_t)l * DIM * DIM;
#pragma unroll
    for (int k = 0; k < 64; k++) acc += ps[k] * loadv(predW, wbase + k * DIM + d, isb);
    int o = g * (DIM * N_PRED) + d * N_PRED + l;
    if (isb) ((__hip_bfloat16*)out)[o] = __float2bfloat16(acc);
    else ((float*)out)[o] = acc;
}

extern "C" void kernel_launch(void* const* d_in, const int* in_sizes, int n_in,
                              void* d_out, int out_size, void* d_ws, size_t ws_size,
                              hipStream_t stream) {
    const void* x     = d_in[0];
    const int*  edge  = (const int*)d_in[1];
    const int*  batch = (const int*)d_in[2];
    const void* W1    = d_in[3];
    const void* b1    = d_in[4];
    const void* W2    = d_in[5];
    const void* b2    = d_in[6];
    const void* gamma = d_in[7];
    const void* beta  = d_in[8];
    const void* alpha = d_in[9];
    const void* pW    = d_in[10];
    const void* pB    = d_in[11];

    float* A = (float*)d_ws;                               // 12.8 MB region
    float* B = A + (size_t)N_NODES * DIM;                  // 12.8 MB region
    double* stats = (double*)(B + (size_t)N_NODES * DIM);  // 128 doubles
    unsigned int* poolEnc = (unsigned int*)(stats + 128);  // 20480 u32
    int* dflag = (int*)(poolEnc + N_PRED * N_GRAPHS * DIM);
    unsigned int* deg     = (unsigned int*)(dflag + 1);    // 50000
    unsigned int* rowptr  = deg + N_NODES;                 // 50000
    unsigned int* cursor  = rowptr + N_NODES;              // 50000
    unsigned int* bsum    = cursor + N_NODES;              // 256
    unsigned int* srclist = bsum + 256;                    // 800000
    unsigned short* Wpack = (unsigned short*)(srclist + N_EDGES);  // 8*4096 bf16

    size_t needCSR  = (size_t)((char*)srclist + 0 - (char*)d_ws) + N_EDGES * 4;
    size_t needFull = (size_t)((char*)(Wpack + 8 * 4096) - (char*)d_ws);
    bool useCSR  = ws_size >= needCSR;
    bool useMFMA = ws_size >= needFull && useCSR;

    const int* esrc = edge;
    const int* edst = edge + N_EDGES;
    const int ND = N_NODES * DIM;  // 3,200,000

    // bf16 sub-buffers inside the A/B fp32 regions (MFMA path):
    unsigned short* Hb = (unsigned short*)A;                        // h,   6.4 MB
    unsigned short* Cb = (unsigned short*)A + (size_t)N_NODES * DIM;  // relu out
    unsigned short* Xb = (unsigned short*)B;                        // agg, 6.4 MB
    float* Zf = B;                                                  // z fp32

    detect_dtype<<<1, 256, 0, stream>>>((const unsigned int*)x, dflag);
    zero_u32<<<(N_PRED * N_GRAPHS * DIM + 255) / 256, 256, 0, stream>>>(poolEnc,
                                                                        N_PRED * N_GRAPHS * DIM);

    if (useCSR) {
        zero_u32<<<SCAN_BLOCKS, 256, 0, stream>>>(deg, N_NODES);
        hist_deg<<<(N_EDGES + 255) / 256, 256, 0, stream>>>(edst, deg);
        deg_block_sums<<<SCAN_BLOCKS, 256, 0, stream>>>(deg, bsum);
        scan_bsums<<<1, 256, 0, stream>>>(bsum);
        scan_write<<<SCAN_BLOCKS, 256, 0, stream>>>(deg, bsum, rowptr, cursor);
        fill_csr<<<(N_EDGES + 255) / 256, 256, 0, stream>>>(esrc, edst, cursor, srclist);
    }

    if (useMFMA) {
        pack_w<<<8, 256, 0, stream>>>(W1, W2, Wpack, dflag);
        convert_pool_b<<<ND / 256, 256, 0, stream>>>(x, Hb, batch, poolEnc, dflag);
        for (int l = 0; l < N_GIN; l++) {
            size_t bOff = (size_t)l * DIM;
            gather_agg_b<<<N_NODES / 4, 256, 0, stream>>>(Hb, Xb, rowptr, deg, srclist);
            mm_mfma<true><<<(N_NODES + 63) / 64, 256, 0, stream>>>(
                Xb, Wpack + (size_t)l * 4096, b1, bOff, Cb, dflag);
            mm_mfma<false><<<(N_NODES + 63) / 64, 256, 0, stream>>>(
                Cb, Wpack + (size_t)(4 + l) * 4096, b2, bOff, Zf, dflag);
            zero_u32<<<1, 256, 0, stream>>>((unsigned int*)stats, 256);
            col_stats<<<256, 256, 0, stream>>>(Zf, stats);
            bn_prelu_pool_b<<<ND / 256, 256, 0, stream>>>(
                Zf, Hb, stats, gamma, beta, bOff, alpha, batch,
                poolEnc + (size_t)(l + 1) * N_GRAPHS * DIM, dflag);
        }
    } else {
        // round-3 proven fallback (fp32 scalar mm)
        convert_pool_f<<<ND / 256, 256, 0, stream>>>(x, A, batch, poolEnc, dflag);
        for (int l = 0; l < N_GIN; l++) {
            size_t wOff = (size_t)l * DIM * DIM;
            size_t bOff = (size_t)l * DIM;
            if (useCSR) {
                // fp32 gather via scatter-free path is bf16-only; reuse scatter here
                copy_f4<<<(ND / 4 + 255) / 256, 256, 0, stream>>>((const float4*)A, (float4*)B,
                                                                  ND / 4);
                edge_scatter<<<(N_EDGES * 16) / 256, 256, 0, stream>>>(esrc, edst, A, B);
            } else {
                copy_f4<<<(ND / 4 + 255) / 256, 256, 0, stream>>>((const float4*)A, (float4*)B,
                                                                  ND / 4);
                edge_scatter<<<(N_EDGES * 16) / 256, 256, 0, stream>>>(esrc, edst, A, B);
            }
            mm64<true, false><<<N_NODES / 4, 256, 0, stream>>>(B, W1, wOff, b1, bOff, A, nullptr,
                                                               dflag);
            zero_u32<<<1, 256, 0, stream>>>((unsigned int*)stats, 256);
            mm64<false, true><<<N_NODES / 4, 256, 0, stream>>>(A, W2, wOff, b2, bOff, B, stats,
                                                               dflag);
            bn_prelu_pool_f<<<ND / 256, 256, 0, stream>>>(
                B, A, stats, gamma, beta, bOff, alpha, batch,
                poolEnc + (size_t)(l + 1) * N_GRAPHS * DIM, dflag);
        }
    }
    pred_head<<<N_PRED * N_GRAPHS, DIM, 0, stream>>>(poolEnc, pW, pB, d_out, dflag);
}